// Round 19
// baseline (62.544 us; speedup 1.0000x reference)
//
#include <hip/hip_runtime.h>
#include <hip/hip_bf16.h>

// Problem constants
#define BB 32
#define GG 1024
#define VV 10000
#define KHID 1024
#define MM 128
#define NCHUNK 625   // 625 * 16 = 10000 rows exactly
#define GEMM_GRID 256
#define GEMM_REP 5   // DIAGNOSTIC: 5 reps in ONE dispatch -> surfaces in top-5

typedef __attribute__((ext_vector_type(8))) short short8;
typedef __attribute__((ext_vector_type(4))) float f32x4;

// pack 2 f32 -> 1 u32 of 2 bf16 (RNE); compiler emits v_cvt_pk_bf16_f32
__device__ __forceinline__ unsigned int pk2(float lo, float hi) {
    __hip_bfloat162 h = __float22bfloat162_rn(make_float2(lo, hi));
    union { __hip_bfloat162 h; unsigned int u; } cv; cv.h = h;
    return cv.u;
}

// bf16 bits -> f32
__device__ __forceinline__ float bfu(unsigned short u) {
    union { unsigned int u; float f; } v; v.u = (unsigned int)u << 16;
    return v.f;
}

// LDS-only barrier: does NOT drain vmcnt (prefetches stay in flight)
__device__ __forceinline__ void lds_barrier() {
    asm volatile("s_waitcnt lgkmcnt(0)" ::: "memory");
    __builtin_amdgcn_s_barrier();
    asm volatile("" ::: "memory");
}

// ---------------------------------------------------------------------------
// K1 DIAGNOSTIC: r16's gemm body repeated GEMM_REP times inside one dispatch
// (idempotent -> same T). B prologue runs once (as in r16). Per-rep cost ==
// r16's steady state + one initial A-load stall. Dispatch ~87us -> top-5,
// exposing MfmaUtil / VALUBusy / FETCH / Occupancy for the gemm itself.
// ---------------------------------------------------------------------------
__global__ __launch_bounds__(512, 2) void k_gemm(const float* __restrict__ A,
                                                 const float* __restrict__ Wfc,
                                                 unsigned short* __restrict__ T) {
    const int tid = threadIdx.x;
    const int w = tid >> 6, lane = tid & 63;
    const int r16 = lane & 15, g = lane >> 4;
    const int kbase = w * 128;

    // prologue: build B fragment regs from f32 W (second-half rows), transposed
    const float* Wg = Wfc + (size_t)KHID * MM;
    short8 breg[4][8];
#pragma unroll
    for (int kt = 0; kt < 4; ++kt)
#pragma unroll
        for (int t = 0; t < 8; ++t) {
            const float* wp = Wg + (size_t)(kbase + kt * 32 + g * 8) * MM + t * 16 + r16;
            unsigned int* bu = (unsigned int*)&breg[kt][t];
            bu[0] = pk2(wp[0 * MM], wp[1 * MM]);
            bu[1] = pk2(wp[2 * MM], wp[3 * MM]);
            bu[2] = pk2(wp[4 * MM], wp[5 * MM]);
            bu[3] = pk2(wp[6 * MM], wp[7 * MM]);
        }

    __shared__ float red[8][16][128];  // 64 KB (r16's proven form)
    const int orow = tid >> 5, c4 = (tid & 31) * 4;

    for (int rep = 0; rep < GEMM_REP; ++rep) {
        asm volatile("" ::: "memory");  // keep each rep live (no cross-rep CSE)

        int chunk = blockIdx.x;
        float4 a[8];
        {
            const float* Ap = A + (size_t)(chunk * 16 + r16) * KHID + kbase + g * 8;
#pragma unroll
            for (int kt = 0; kt < 4; ++kt) {
                a[2 * kt]     = *(const float4*)(Ap + kt * 32);
                a[2 * kt + 1] = *(const float4*)(Ap + kt * 32 + 4);
            }
        }

        while (chunk < NCHUNK) {
            const int next = chunk + GEMM_GRID;

            f32x4 acc[8];
#pragma unroll
            for (int t = 0; t < 8; ++t) acc[t] = (f32x4){0.f, 0.f, 0.f, 0.f};
#pragma unroll
            for (int kt = 0; kt < 4; ++kt) {
                short8 af;
                unsigned int* au = (unsigned int*)&af;
                au[0] = pk2(a[2 * kt].x, a[2 * kt].y);
                au[1] = pk2(a[2 * kt].z, a[2 * kt].w);
                au[2] = pk2(a[2 * kt + 1].x, a[2 * kt + 1].y);
                au[3] = pk2(a[2 * kt + 1].z, a[2 * kt + 1].w);
#pragma unroll
                for (int t = 0; t < 8; ++t)
                    acc[t] = __builtin_amdgcn_mfma_f32_16x16x32_bf16(af, breg[kt][t],
                                                                     acc[t], 0, 0, 0);
            }

            if (next < NCHUNK) {
                const float* Ap = A + (size_t)(next * 16 + r16) * KHID + kbase + g * 8;
#pragma unroll
                for (int kt = 0; kt < 4; ++kt) {
                    a[2 * kt]     = *(const float4*)(Ap + kt * 32);
                    a[2 * kt + 1] = *(const float4*)(Ap + kt * 32 + 4);
                }
            }

#pragma unroll
            for (int t = 0; t < 8; ++t)
#pragma unroll
                for (int r = 0; r < 4; ++r)
                    red[w][g * 4 + r][t * 16 + r16] = acc[t][r];
            lds_barrier();

            float4 s = *(const float4*)&red[0][orow][c4];
#pragma unroll
            for (int sl = 1; sl < 8; ++sl) {
                float4 p = *(const float4*)&red[sl][orow][c4];
                s.x += p.x; s.y += p.y; s.z += p.z; s.w += p.w;
            }
            *(uint2*)&T[(size_t)(chunk * 16 + orow) * MM + c4] =
                make_uint2(pk2(s.x, s.y), pk2(s.z, s.w));
            lds_barrier();  // red reused next chunk

            chunk = next;
        }
    }
}

// ---------------------------------------------------------------------------
// K2: BN stats, grid (32, 32), batched-8 register gather. (r16-identical)
// ---------------------------------------------------------------------------
__global__ __launch_bounds__(256) void k_stats(const unsigned short* __restrict__ T,
                                               const int* __restrict__ gPos,
                                               float* __restrict__ ps1,
                                               float* __restrict__ ps2) {
    const int b = blockIdx.y, c = blockIdx.x;
    const int tid = threadIdx.x;

    __shared__ int posl[32];
    __shared__ float r1[4][128], r2[4][128];

    if (tid < 32) posl[tid] = gPos[b * GG + c * 32 + tid];
    __syncthreads();

    const int m = tid & 63, q = tid >> 6;
    unsigned int uu[8];
#pragma unroll
    for (int i = 0; i < 8; ++i)
        uu[i] = *(const unsigned int*)&T[(size_t)posl[q * 8 + i] * MM + m * 2];

    float s1a = 0.f, s1b = 0.f, s2a = 0.f, s2b = 0.f;
#pragma unroll
    for (int i = 0; i < 8; ++i) {
        float t0 = bfu((unsigned short)(uu[i] & 0xFFFFu));
        float t1 = bfu((unsigned short)(uu[i] >> 16));
        s1a += t0; s2a += t0 * t0;
        s1b += t1; s2b += t1 * t1;
    }
    r1[q][m * 2] = s1a; r1[q][m * 2 + 1] = s1b;
    r2[q][m * 2] = s2a; r2[q][m * 2 + 1] = s2b;
    __syncthreads();
    if (tid < 128) {
        ps1[((size_t)b * 32 + c) * MM + tid] = r1[0][tid] + r1[1][tid] + r1[2][tid] + r1[3][tid];
        ps2[((size_t)b * 32 + c) * MM + tid] = r2[0][tid] + r2[1][tid] + r2[2][tid] + r2[3][tid];
    }
}

// ---------------------------------------------------------------------------
// K3: final, grid (32, 32), batched-8 gather + combine. (r16-identical)
// ---------------------------------------------------------------------------
__global__ __launch_bounds__(256) void k_final(const unsigned short* __restrict__ T,
                                               const int* __restrict__ gPos,
                                               const float* __restrict__ ps1,
                                               const float* __restrict__ ps2,
                                               const float* __restrict__ gamma,
                                               const float* __restrict__ beta,
                                               const float* __restrict__ W2,
                                               const float* __restrict__ b2,
                                               float* __restrict__ out) {
    const int b = blockIdx.y, gc = blockIdx.x;
    const int tid = threadIdx.x;

    __shared__ float ssc[128], ssh[128];
    __shared__ int posl[32];
    if (tid < 32) posl[tid] = gPos[b * GG + gc * 32 + tid];
    if (tid >= 128) {
        int mcol = tid - 128;
        float S1 = 0.f, S2 = 0.f;
#pragma unroll
        for (int cc = 0; cc < 32; ++cc) {
            S1 += ps1[((size_t)b * 32 + cc) * MM + mcol];
            S2 += ps2[((size_t)b * 32 + cc) * MM + mcol];
        }
        float mean = S1 * (1.f / 1024.f);
        float var  = S2 * (1.f / 1024.f) - mean * mean;
        float rstd = rsqrtf(var + 1e-5f);
        float sc = gamma[mcol] * rstd;
        ssc[mcol] = sc;
        ssh[mcol] = beta[mcol] - sc * mean;
    }
    __syncthreads();

    const int wave = tid >> 6, lane = tid & 63;
    const int m0 = lane * 2, m1 = lane * 2 + 1;
    const float sc0 = ssc[m0], sh0 = ssh[m0], w20 = W2[m0];
    const float sc1 = ssc[m1], sh1 = ssh[m1], w21 = W2[m1];
    const float bias = b2[0];

    unsigned int uu[8];
#pragma unroll
    for (int i = 0; i < 8; ++i)
        uu[i] = *(const unsigned int*)&T[(size_t)posl[wave * 8 + i] * MM + m0];

#pragma unroll
    for (int i = 0; i < 8; ++i) {
        float t0 = bfu((unsigned short)(uu[i] & 0xFFFFu));
        float t1 = bfu((unsigned short)(uu[i] >> 16));
        float val = fmaxf(sc0 * t0 + sh0, 0.f) * w20 + fmaxf(sc1 * t1 + sh1, 0.f) * w21;
#pragma unroll
        for (int off = 32; off; off >>= 1) val += __shfl_xor(val, off, 64);
        if (lane == 0)
            out[b * GG + gc * 32 + wave * 8 + i] = 1.f / (1.f + __expf(-(val + bias)));
    }
}

// ---------------------------------------------------------------------------
extern "C" void kernel_launch(void* const* d_in, const int* in_sizes, int n_in,
                              void* d_out, int out_size, void* d_ws, size_t ws_size,
                              hipStream_t stream) {
    const int*   gPos  = (const int*)d_in[3];
    const float* A     = (const float*)d_in[4];
    const float* Wfc   = (const float*)d_in[11];
    const float* gamma = (const float*)d_in[13];
    const float* beta  = (const float*)d_in[14];
    const float* W2    = (const float*)d_in[15];
    const float* b2    = (const float*)d_in[16];
    float* out = (float*)d_out;

    char* ws = (char*)d_ws;
    unsigned short* T = (unsigned short*)ws;        // 2.56 MB bf16
    float* ps1 = (float*)(ws + (4 << 20));          // 512 KB
    float* ps2 = (float*)(ws + (8 << 20));          // 512 KB

    hipLaunchKernelGGL(k_gemm, dim3(GEMM_GRID), dim3(512), 0, stream, A, Wfc, T);
    hipLaunchKernelGGL(k_stats, dim3(32, BB), dim3(256), 0, stream, T, gPos, ps1, ps2);
    hipLaunchKernelGGL(k_final, dim3(32, BB), dim3(256), 0, stream, T, gPos, ps1, ps2,
                       gamma, beta, W2, b2, out);
}

// Round 20
// 33.055 us; speedup vs baseline: 1.8921x; 1.8921x over previous
//
#include <hip/hip_runtime.h>
#include <hip/hip_bf16.h>

// Problem constants
#define BB 32
#define GG 1024
#define VV 10000
#define KHID 1024
#define MM 128
#define NCHUNK 625   // 625 * 16 = 10000 rows exactly
#define GEMM_GRID 256

typedef __attribute__((ext_vector_type(8))) short short8;
typedef __attribute__((ext_vector_type(4))) float f32x4;

// pack 2 f32 -> 1 u32 of 2 bf16 (RNE); compiler emits v_cvt_pk_bf16_f32
__device__ __forceinline__ unsigned int pk2(float lo, float hi) {
    __hip_bfloat162 h = __float22bfloat162_rn(make_float2(lo, hi));
    union { __hip_bfloat162 h; unsigned int u; } cv; cv.h = h;
    return cv.u;
}

// bf16 bits -> f32
__device__ __forceinline__ float bfu(unsigned short u) {
    union { unsigned int u; float f; } v; v.u = (unsigned int)u << 16;
    return v.f;
}

// LDS-only barrier: does NOT drain vmcnt (prefetches stay in flight)
__device__ __forceinline__ void lds_barrier() {
    asm volatile("s_waitcnt lgkmcnt(0)" ::: "memory");
    __builtin_amdgcn_s_barrier();
    asm volatile("" ::: "memory");
}

// ---------------------------------------------------------------------------
// K1: T(bf16) = A @ Wg. r16 structure with ONE change: breg is PINNED into
// VGPRs via an inline-asm anchor after the prologue. r19's counters proved
// (VGPR_Count=112 < 128 needed) that the compiler was sinking the loop-
// invariant B loads into the chunk loop -- re-fetching 32 KB/wave/chunk from
// L2 (~160 MB/gemm). The asm output cannot be rematerialized, forcing the
// B-slab to stay register-resident; the inner loop then has zero B traffic.
// ---------------------------------------------------------------------------
__global__ __launch_bounds__(512, 2) void k_gemm(const float* __restrict__ A,
                                                 const float* __restrict__ Wfc,
                                                 unsigned short* __restrict__ T) {
    const int tid = threadIdx.x;
    const int w = tid >> 6, lane = tid & 63;
    const int r16 = lane & 15, g = lane >> 4;
    const int kbase = w * 128;

    int chunk = blockIdx.x;

    // issue first chunk's A loads ASAP (fly under the B prologue)
    float4 a[8];
    {
        const float* Ap = A + (size_t)(chunk * 16 + r16) * KHID + kbase + g * 8;
#pragma unroll
        for (int kt = 0; kt < 4; ++kt) {
            a[2 * kt]     = *(const float4*)(Ap + kt * 32);
            a[2 * kt + 1] = *(const float4*)(Ap + kt * 32 + 4);
        }
    }

    // prologue: build B fragment regs from f32 W (second-half rows), transposed
    const float* Wg = Wfc + (size_t)KHID * MM;
    short8 breg[4][8];
#pragma unroll
    for (int kt = 0; kt < 4; ++kt)
#pragma unroll
        for (int t = 0; t < 8; ++t) {
            const float* wp = Wg + (size_t)(kbase + kt * 32 + g * 8) * MM + t * 16 + r16;
            unsigned int* bu = (unsigned int*)&breg[kt][t];
            bu[0] = pk2(wp[0 * MM], wp[1 * MM]);
            bu[1] = pk2(wp[2 * MM], wp[3 * MM]);
            bu[2] = pk2(wp[4 * MM], wp[5 * MM]);
            bu[3] = pk2(wp[6 * MM], wp[7 * MM]);
        }

    // PIN: force breg values to live in VGPRs across the loop (the asm
    // "modifies" them, so the loads above cannot be rematerialized inside).
#pragma unroll
    for (int kt = 0; kt < 4; ++kt)
#pragma unroll
        for (int t = 0; t < 8; ++t)
            asm volatile("" : "+v"(breg[kt][t]));

    __shared__ float red[8][16][128];  // 64 KB (r16's proven form)

    const int orow = tid >> 5, c4 = (tid & 31) * 4;  // store mapping

    while (chunk < NCHUNK) {
        const int next = chunk + GEMM_GRID;

        // MFMA phase: consume a[] (a[] dead after -> reused by prefetch)
        f32x4 acc[8];
#pragma unroll
        for (int t = 0; t < 8; ++t) acc[t] = (f32x4){0.f, 0.f, 0.f, 0.f};
#pragma unroll
        for (int kt = 0; kt < 4; ++kt) {
            short8 af;
            unsigned int* au = (unsigned int*)&af;
            au[0] = pk2(a[2 * kt].x, a[2 * kt].y);
            au[1] = pk2(a[2 * kt].z, a[2 * kt].w);
            au[2] = pk2(a[2 * kt + 1].x, a[2 * kt + 1].y);
            au[3] = pk2(a[2 * kt + 1].z, a[2 * kt + 1].w);
#pragma unroll
            for (int t = 0; t < 8; ++t)
                acc[t] = __builtin_amdgcn_mfma_f32_16x16x32_bf16(af, breg[kt][t], acc[t],
                                                                 0, 0, 0);
        }

        // prefetch next chunk's A (in flight across the LDS phase below)
        if (next < NCHUNK) {
            const float* Ap = A + (size_t)(next * 16 + r16) * KHID + kbase + g * 8;
#pragma unroll
            for (int kt = 0; kt < 4; ++kt) {
                a[2 * kt]     = *(const float4*)(Ap + kt * 32);
                a[2 * kt + 1] = *(const float4*)(Ap + kt * 32 + 4);
            }
        }

        // 8-slab reduce: every wave writes its own slab, ONE barrier
#pragma unroll
        for (int t = 0; t < 8; ++t)
#pragma unroll
            for (int r = 0; r < 4; ++r)
                red[w][g * 4 + r][t * 16 + r16] = acc[t][r];
        lds_barrier();

        // all 512 threads: sum 8 slabs, convert, store
        float4 s = *(const float4*)&red[0][orow][c4];
#pragma unroll
        for (int sl = 1; sl < 8; ++sl) {
            float4 p = *(const float4*)&red[sl][orow][c4];
            s.x += p.x; s.y += p.y; s.z += p.z; s.w += p.w;
        }
        *(uint2*)&T[(size_t)(chunk * 16 + orow) * MM + c4] =
            make_uint2(pk2(s.x, s.y), pk2(s.z, s.w));
        lds_barrier();  // red reused next chunk

        chunk = next;
    }
}

// ---------------------------------------------------------------------------
// K2: BN stats, grid (32, 32), batched-8 register gather. (r16-identical)
// ---------------------------------------------------------------------------
__global__ __launch_bounds__(256) void k_stats(const unsigned short* __restrict__ T,
                                               const int* __restrict__ gPos,
                                               float* __restrict__ ps1,
                                               float* __restrict__ ps2) {
    const int b = blockIdx.y, c = blockIdx.x;
    const int tid = threadIdx.x;

    __shared__ int posl[32];
    __shared__ float r1[4][128], r2[4][128];

    if (tid < 32) posl[tid] = gPos[b * GG + c * 32 + tid];
    __syncthreads();

    const int m = tid & 63, q = tid >> 6;
    unsigned int uu[8];
#pragma unroll
    for (int i = 0; i < 8; ++i)
        uu[i] = *(const unsigned int*)&T[(size_t)posl[q * 8 + i] * MM + m * 2];

    float s1a = 0.f, s1b = 0.f, s2a = 0.f, s2b = 0.f;
#pragma unroll
    for (int i = 0; i < 8; ++i) {
        float t0 = bfu((unsigned short)(uu[i] & 0xFFFFu));
        float t1 = bfu((unsigned short)(uu[i] >> 16));
        s1a += t0; s2a += t0 * t0;
        s1b += t1; s2b += t1 * t1;
    }
    r1[q][m * 2] = s1a; r1[q][m * 2 + 1] = s1b;
    r2[q][m * 2] = s2a; r2[q][m * 2 + 1] = s2b;
    __syncthreads();
    if (tid < 128) {
        ps1[((size_t)b * 32 + c) * MM + tid] = r1[0][tid] + r1[1][tid] + r1[2][tid] + r1[3][tid];
        ps2[((size_t)b * 32 + c) * MM + tid] = r2[0][tid] + r2[1][tid] + r2[2][tid] + r2[3][tid];
    }
}

// ---------------------------------------------------------------------------
// K3: final, grid (32, 32), batched-8 gather + combine. (r16-identical)
// ---------------------------------------------------------------------------
__global__ __launch_bounds__(256) void k_final(const unsigned short* __restrict__ T,
                                               const int* __restrict__ gPos,
                                               const float* __restrict__ ps1,
                                               const float* __restrict__ ps2,
                                               const float* __restrict__ gamma,
                                               const float* __restrict__ beta,
                                               const float* __restrict__ W2,
                                               const float* __restrict__ b2,
                                               float* __restrict__ out) {
    const int b = blockIdx.y, gc = blockIdx.x;
    const int tid = threadIdx.x;

    __shared__ float ssc[128], ssh[128];
    __shared__ int posl[32];
    if (tid < 32) posl[tid] = gPos[b * GG + gc * 32 + tid];
    if (tid >= 128) {
        int mcol = tid - 128;
        float S1 = 0.f, S2 = 0.f;
#pragma unroll
        for (int cc = 0; cc < 32; ++cc) {
            S1 += ps1[((size_t)b * 32 + cc) * MM + mcol];
            S2 += ps2[((size_t)b * 32 + cc) * MM + mcol];
        }
        float mean = S1 * (1.f / 1024.f);
        float var  = S2 * (1.f / 1024.f) - mean * mean;
        float rstd = rsqrtf(var + 1e-5f);
        float sc = gamma[mcol] * rstd;
        ssc[mcol] = sc;
        ssh[mcol] = beta[mcol] - sc * mean;
    }
    __syncthreads();

    const int wave = tid >> 6, lane = tid & 63;
    const int m0 = lane * 2, m1 = lane * 2 + 1;
    const float sc0 = ssc[m0], sh0 = ssh[m0], w20 = W2[m0];
    const float sc1 = ssc[m1], sh1 = ssh[m1], w21 = W2[m1];
    const float bias = b2[0];

    unsigned int uu[8];
#pragma unroll
    for (int i = 0; i < 8; ++i)
        uu[i] = *(const unsigned int*)&T[(size_t)posl[wave * 8 + i] * MM + m0];

#pragma unroll
    for (int i = 0; i < 8; ++i) {
        float t0 = bfu((unsigned short)(uu[i] & 0xFFFFu));
        float t1 = bfu((unsigned short)(uu[i] >> 16));
        float val = fmaxf(sc0 * t0 + sh0, 0.f) * w20 + fmaxf(sc1 * t1 + sh1, 0.f) * w21;
#pragma unroll
        for (int off = 32; off; off >>= 1) val += __shfl_xor(val, off, 64);
        if (lane == 0)
            out[b * GG + gc * 32 + wave * 8 + i] = 1.f / (1.f + __expf(-(val + bias)));
    }
}

// ---------------------------------------------------------------------------
extern "C" void kernel_launch(void* const* d_in, const int* in_sizes, int n_in,
                              void* d_out, int out_size, void* d_ws, size_t ws_size,
                              hipStream_t stream) {
    const int*   gPos  = (const int*)d_in[3];
    const float* A     = (const float*)d_in[4];
    const float* Wfc   = (const float*)d_in[11];
    const float* gamma = (const float*)d_in[13];
    const float* beta  = (const float*)d_in[14];
    const float* W2    = (const float*)d_in[15];
    const float* b2    = (const float*)d_in[16];
    float* out = (float*)d_out;

    char* ws = (char*)d_ws;
    unsigned short* T = (unsigned short*)ws;        // 2.56 MB bf16
    float* ps1 = (float*)(ws + (4 << 20));          // 512 KB
    float* ps2 = (float*)(ws + (8 << 20));          // 512 KB

    hipLaunchKernelGGL(k_gemm, dim3(GEMM_GRID), dim3(512), 0, stream, A, Wfc, T);
    hipLaunchKernelGGL(k_stats, dim3(32, BB), dim3(256), 0, stream, T, gPos, ps1, ps2);
    hipLaunchKernelGGL(k_final, dim3(32, BB), dim3(256), 0, stream, T, gPos, ps1, ps2,
                       gamma, beta, W2, b2, out);
}